// Round 2
// baseline (708.386 us; speedup 1.0000x reference)
//
#include <hip/hip_runtime.h>

#define NB 2
#define NH 12
#define NS 256
#define NE 64
#define NC 768   // NH*NE
#define NL 25
#define EC 32    // e-chunk per staging iteration (half a head)
#define NIT 24   // NC/EC
#define SRS 36   // sR row stride (32 data + 4 pad) -> conflict-free strided reads

// out[b,j,l,i] = bias[l] + sum_{k,e} p[b,k,i,j] * (v[b,k,j,e] + rel[b,i,j,k*64+e]) * W[l,k*64+e]
// p is folded into the staged tile: sR[i][e] = p[b,k,i,j]*(rel+v), so the hot
// loop is a pure 768-deep contraction with a 4x5 register tile per thread.
__global__ __launch_bounds__(320) void tmhs_main(
    const float* __restrict__ p,    // (B,H,S,S)
    const float* __restrict__ v,    // (B,H,S,E)
    const float* __restrict__ rel,  // (B,S,S,C)
    const float* __restrict__ W,    // (L,C)
    const float* __restrict__ bias, // (L,)
    float* __restrict__ out)        // (B,S,L,S)
{
    // Bank math (32 banks): compute reads row ig+64q, stride 36 floats:
    //   bank = (36*(ig+64q) + 4*e4) % 32 = (4*ig + 4*e4) % 32  (64*36 % 32 == 0)
    // -> lanes 0..7 sweep all 32 banks: conflict-free b128 reads.
    __shared__ float sR[NS][SRS];   // 36864 B : p-scaled (rel+v), 256 rows x 32
    __shared__ float sW[NL][EC];    // 3200 B
    __shared__ float sBias[32];

    const int tid = threadIdx.x;
    const int j   = blockIdx.x & 255;
    const int b   = blockIdx.x >> 8;

    if (tid < NL) sBias[tid] = bias[tid];

    const int ig = tid & 63;        // i within group; thread's i's: ig + 64q
    const int lg = tid >> 6;        // wave 0..4 -> labels 5*lg .. 5*lg+4
    const int l0 = lg * 5;

    float acc[4][5];
#pragma unroll
    for (int q = 0; q < 4; ++q)
#pragma unroll
        for (int u = 0; u < 5; ++u) acc[q][u] = 0.f;

    const int rbase = tid >> 2;     // staging: 0..63, rows rbase + 64q
    const int part  = tid & 3;      // staging: 8-float segment within chunk

    for (int m = 0; m < NIT; ++m) {
        const int k  = m >> 1;
        const int eh = (m & 1) << 5;     // 0 or 32 within the head
        __syncthreads();                 // protect sR/sW from prev readers
        if (tid < 256) {
            // v segment (8 floats), identical for all 4 rows of this thread
            const float4* vp = (const float4*)(v + (((b*NH + k)*NS + j) << 6) + eh + part*8);
            const float4 v0 = vp[0], v1 = vp[1];
            const int pbase = ((b*NH + k)*NS)*NS + j;
#pragma unroll
            for (int q = 0; q < 4; ++q) {
                const int r  = rbase + (q << 6);
                const float pr = p[pbase + r*NS];
                const float4* rs = (const float4*)(rel + ((b*NS + r)*NS + j)*NC + k*64 + eh + part*8);
                float4 a0 = rs[0], a1 = rs[1];
                a0.x = pr*(a0.x + v0.x); a0.y = pr*(a0.y + v0.y);
                a0.z = pr*(a0.z + v0.z); a0.w = pr*(a0.w + v0.w);
                a1.x = pr*(a1.x + v1.x); a1.y = pr*(a1.y + v1.y);
                a1.z = pr*(a1.z + v1.z); a1.w = pr*(a1.w + v1.w);
                // write banks: (4*rbase + 8*part)%32 -> 8-lane full sweep, conflict-free
                float4* dst = (float4*)&sR[r][part*8];
                dst[0] = a0; dst[1] = a1;
            }
        } else {
            const int t = tid - 256;         // wave 4 stages the W chunk
            const int wcol = k*64 + eh;
            for (int q2 = t; q2 < NL*8; q2 += 64) {
                const int row = q2 >> 3, c4 = q2 & 7;
                *(float4*)&sW[row][c4*4] = *(const float4*)(W + row*NC + wcol + c4*4);
            }
        }
        __syncthreads();

#pragma unroll
        for (int e4 = 0; e4 < 8; ++e4) {
            float4 r4[4], w4[5];
#pragma unroll
            for (int q = 0; q < 4; ++q) r4[q] = *(const float4*)&sR[ig + (q << 6)][e4*4];
#pragma unroll
            for (int u = 0; u < 5; ++u) w4[u] = *(const float4*)&sW[l0 + u][e4*4]; // broadcast
#pragma unroll
            for (int q = 0; q < 4; ++q)
#pragma unroll
                for (int u = 0; u < 5; ++u) {
                    acc[q][u] = fmaf(r4[q].x, w4[u].x, acc[q][u]);
                    acc[q][u] = fmaf(r4[q].y, w4[u].y, acc[q][u]);
                    acc[q][u] = fmaf(r4[q].z, w4[u].z, acc[q][u]);
                    acc[q][u] = fmaf(r4[q].w, w4[u].w, acc[q][u]);
                }
        }
    }

    // coalesced epilogue: lane -> i contiguous in out[b,j,l,i]
    const int ob = ((b*NS + j)*NL)*NS;
#pragma unroll
    for (int u = 0; u < 5; ++u)
#pragma unroll
        for (int q = 0; q < 4; ++q)
            out[ob + (l0 + u)*NS + ig + (q << 6)] = acc[q][u] + sBias[l0 + u];
}

extern "C" void kernel_launch(void* const* d_in, const int* in_sizes, int n_in,
                              void* d_out, int out_size, void* d_ws, size_t ws_size,
                              hipStream_t stream) {
    const float* p    = (const float*)d_in[0];
    const float* v    = (const float*)d_in[1];
    const float* rel  = (const float*)d_in[2];
    const float* W    = (const float*)d_in[3];
    const float* bias = (const float*)d_in[4];
    float* out = (float*)d_out;
    tmhs_main<<<dim3(NB * NS), dim3(320), 0, stream>>>(p, v, rel, W, bias, out);
}

// Round 3
// 611.981 us; speedup vs baseline: 1.1575x; 1.1575x over previous
//
#include <hip/hip_runtime.h>

#define NB 2
#define NH 12
#define NS 256
#define NE 64
#define NC 768   // NH*NE
#define NL 25

// out[b,j,l,i] = bias[l] + sum_{k,e} p[b,k,i,j] * (v[b,k,j,e] + rel[b,i,j,k*64+e]) * W[l,k*64+e]
//
// Key structural choice this round: W is read via SCALAR loads (wave-uniform
// address forced by readfirstlane on the wave id) so the LDS pipe -- one per
// CU, ~12 cyc per wave b128 even for broadcasts -- only carries the A-tile.
// Per wave-e4-step: 1 ds_read_b128 + 7 s_load_dwordx4 + 28 v_fma (SGPR src0).
__global__ __launch_bounds__(256) void tmhs_main(
    const float* __restrict__ p,    // (B,H,S,S)
    const float* __restrict__ v,    // (B,H,S,E)
    const float* __restrict__ rel,  // (B,S,S,C)
    const float* __restrict__ W,    // (L,C)
    const float* __restrict__ bias, // (L,)
    float* __restrict__ out)        // (B,S,L,S)
{
    // stride 68 floats: compute-read bank start = (68*ig+4*e4)%32 = 4*(ig+e4)%32
    // -> each fixed 8-lane group sweeps all 32 banks once: conflict-free b128.
    __shared__ float sR[64][68];    // 17.4 KB -> 8 blocks/CU fits easily

    const int tid = threadIdx.x;
    const int bx  = blockIdx.x;
    const int it  = bx & 3;          // i-tile (4 x 64)
    const int j   = (bx >> 2) & 255;
    const int b   = bx >> 10;
    const int i0  = it << 6;

    const int ig = tid & 63;
    // force wave id uniform so W/bias addresses are provably wave-uniform -> s_load
    const int wv = __builtin_amdgcn_readfirstlane(tid >> 6);   // 0..3
    const int l0 = wv * 6;          // labels l0..l0+6; dups at 6,12,18 are
                                    // bitwise-identical (same data, same fma order)

    float acc[7] = {0.f,0.f,0.f,0.f,0.f,0.f,0.f};

    const int row  = tid >> 2;      // 0..63 : one quarter-row (16 floats) per thread
    const int part = tid & 3;

    for (int k = 0; k < NH; ++k) {
        __syncthreads();            // protect sR from previous iteration's readers
        {
            // p folded into the staged tile: sR[i][e] = p * (rel + v)
            const float  pr = p[((b*NH + k)*NS + (i0 + row))*NS + j];
            const float4* vp = (const float4*)(v + (((b*NH + k)*NS + j) << 6) + part*16);
            const float4* rs = (const float4*)(rel + ((b*NS + (i0+row))*NS + j)*NC + k*64 + part*16);
            float4* dst = (float4*)&sR[row][part*16];
#pragma unroll
            for (int q = 0; q < 4; ++q) {
                float4 a = rs[q];
                const float4 bb = vp[q];
                a.x = pr*(a.x + bb.x); a.y = pr*(a.y + bb.y);
                a.z = pr*(a.z + bb.z); a.w = pr*(a.w + bb.w);
                dst[q] = a;
            }
        }
        __syncthreads();

        const float* wk = W + k*64;
#pragma unroll
        for (int e4 = 0; e4 < 16; ++e4) {
            const float4 r4 = *(const float4*)&sR[ig][e4*4];
#pragma unroll
            for (int u = 0; u < 7; ++u) {
                // uniform address -> s_load_dwordx4; fma reads SGPR directly
                const float4 w4 = *(const float4*)(wk + (l0 + u)*NC + e4*4);
                acc[u] = fmaf(r4.x, w4.x, acc[u]);
                acc[u] = fmaf(r4.y, w4.y, acc[u]);
                acc[u] = fmaf(r4.z, w4.z, acc[u]);
                acc[u] = fmaf(r4.w, w4.w, acc[u]);
            }
        }
    }

    // coalesced epilogue: lane -> i contiguous in out[b,j,l,i]
    const int ob = ((b*NS + j)*NL)*NS + i0 + ig;
#pragma unroll
    for (int u = 0; u < 7; ++u) {
        const int l = l0 + u;       // max 24 < 25; dup labels rewrite identical value
        out[ob + l*NS] = acc[u] + bias[l];
    }
}

extern "C" void kernel_launch(void* const* d_in, const int* in_sizes, int n_in,
                              void* d_out, int out_size, void* d_ws, size_t ws_size,
                              hipStream_t stream) {
    const float* p    = (const float*)d_in[0];
    const float* v    = (const float*)d_in[1];
    const float* rel  = (const float*)d_in[2];
    const float* W    = (const float*)d_in[3];
    const float* bias = (const float*)d_in[4];
    float* out = (float*)d_out;
    tmhs_main<<<dim3(NB * NS * 4), dim3(256), 0, stream>>>(p, v, rel, W, bias, out);
}

// Round 4
// 560.835 us; speedup vs baseline: 1.2631x; 1.0912x over previous
//
#include <hip/hip_runtime.h>
#include <hip/hip_bf16.h>

#define NB 2
#define NH 12
#define NS 256
#define NE 64
#define NC 768   // NH*NE
#define NL 25

#define CH 128   // K-chunk per LDS stage (2 heads)
#define NCH 6    // NC / CH
#define TI 128   // i-tile per block
#define SAS 132  // sA row stride in bf16: 264 B = 8B-aligned (b64 path), 2-way banks (free)

typedef __attribute__((ext_vector_type(8))) short short8;   // MFMA A/B frag (8 bf16)
typedef __attribute__((ext_vector_type(4))) float float4v;  // MFMA acc

__device__ __forceinline__ unsigned short bfb(float x) {
    __hip_bfloat16 h = __float2bfloat16(x);   // RNE
    return *reinterpret_cast<unsigned short*>(&h);
}
__device__ __forceinline__ unsigned int pk2(float x, float y) {
    return (unsigned int)bfb(x) | ((unsigned int)bfb(y) << 16);
}

// W (25x768 fp32) -> Wb (32x768 bf16, rows 25..31 zeroed for the padded M-tile)
__global__ void prep_w(const float* __restrict__ W, unsigned short* __restrict__ Wb) {
    int idx = blockIdx.x * 256 + threadIdx.x;
    if (idx >= 32 * NC) return;
    int row = idx / NC;
    int col = idx - row * NC;
    Wb[idx] = (row < NL) ? bfb(W[row * NC + col]) : (unsigned short)0;
}

// out[b,j,l,i] = bias[l] + sum_c W[l,c] * A[c,i],  A[c,i] = p[b,c>>6,i,j]*(rel[b,i,j,c]+v[b,c>>6,j,c&63])
// MFMA: D(16l x 16i) += Wtile(16l x 32c) * Atile(32c x 16i), K swept in 6 LDS chunks of 128.
__global__ __launch_bounds__(256, 4) void tmhs_mfma(
    const float* __restrict__ p,
    const float* __restrict__ v,
    const float* __restrict__ rel,
    const unsigned short* __restrict__ Wb,   // 32x768 bf16 (prepped)
    const float* __restrict__ bias,
    float* __restrict__ out)
{
    __shared__ unsigned short sA[TI][SAS];   // 33792 B -> 4 blocks/CU

    const int tid = threadIdx.x;
    const int bx  = blockIdx.x;              // 1024 = b(2) * j(256) * ihalf(2)
    const int ih  = bx & 1;
    const int j   = (bx >> 1) & 255;
    const int b   = bx >> 9;
    const int i0  = ih * TI;

    const int lane = tid & 63;
    const int wv   = tid >> 6;               // wave 0..3 -> i sub-range
    const int n15  = lane & 15;
    const int quad = lane >> 4;

    float4v z = {0.f, 0.f, 0.f, 0.f};
    float4v acc[2][2] = {{z, z}, {z, z}};    // [mtile][ntile]

    const int srow  = tid >> 1;              // staging: row 0..127
    const int shalf = tid & 1;               // staging: which head-half of the 128-chunk

    for (int ch = 0; ch < NCH; ++ch) {
        const int kc = ch * CH;
        const int h  = (kc >> 6) + shalf;    // this thread's head during staging
        __syncthreads();                     // protect sA from previous chunk's readers
        {
            const float  pr = p[((b*NH + h)*NS + (i0 + srow))*NS + j];
            const float4* rs = (const float4*)(rel + ((b*NS + i0 + srow)*NS + j)*NC + kc + shalf*64);
            const float4* vs = (const float4*)(v + ((b*NH + h)*NS + j)*NE);
            unsigned int* dst = (unsigned int*)&sA[srow][shalf*64];
#pragma unroll
            for (int q = 0; q < 16; ++q) {
                const float4 rr = rs[q];
                const float4 vv = vs[q];
                uint2 w2;
                w2.x = pk2(pr*(rr.x+vv.x), pr*(rr.y+vv.y));
                w2.y = pk2(pr*(rr.z+vv.z), pr*(rr.w+vv.w));
                *(uint2*)(dst + q*2) = w2;   // ds_write_b64, 2/4-way banks (cheap)
            }
        }
        __syncthreads();

#pragma unroll
        for (int ks = 0; ks < 4; ++ks) {     // 4 x K=32 per chunk
            // A-frag (W): row m = lane&15 (+16 for mtile1), k = quad*8 + 0..7. L1-hot.
            short8 af0 = *(const short8*)(Wb + (     n15)*NC + kc + ks*32 + quad*8);
            short8 af1 = *(const short8*)(Wb + (16 + n15)*NC + kc + ks*32 + quad*8);
#pragma unroll
            for (int nt = 0; nt < 2; ++nt) {
                // B-frag: n = lane&15 -> i row of sA, k = quad*8 + 0..7 contiguous in c
                const unsigned short* bp = &sA[wv*32 + nt*16 + n15][ks*32 + quad*8];
                union { short8 s8; unsigned long long d[2]; } bu;
                bu.d[0] = *(const unsigned long long*)bp;        // ds_read_b64 (2-way, free)
                bu.d[1] = *(const unsigned long long*)(bp + 4);
                acc[0][nt] = __builtin_amdgcn_mfma_f32_16x16x32_bf16(af0, bu.s8, acc[0][nt], 0, 0, 0);
                acc[1][nt] = __builtin_amdgcn_mfma_f32_16x16x32_bf16(af1, bu.s8, acc[1][nt], 0, 0, 0);
            }
        }
    }

    // Epilogue: C/D layout col(i) = lane&15, row(l) = quad*4 + reg (m89-verified).
    const int obase = ((b*NS + j)*NL)*NS;
#pragma unroll
    for (int nt = 0; nt < 2; ++nt) {
        const int ii = i0 + wv*32 + nt*16 + n15;
#pragma unroll
        for (int mt = 0; mt < 2; ++mt) {
#pragma unroll
            for (int r = 0; r < 4; ++r) {
                const int l = mt*16 + quad*4 + r;
                if (l < NL)
                    out[obase + l*NS + ii] = acc[mt][nt][r] + bias[l];
            }
        }
    }
}

extern "C" void kernel_launch(void* const* d_in, const int* in_sizes, int n_in,
                              void* d_out, int out_size, void* d_ws, size_t ws_size,
                              hipStream_t stream) {
    const float* p    = (const float*)d_in[0];
    const float* v    = (const float*)d_in[1];
    const float* rel  = (const float*)d_in[2];
    const float* W    = (const float*)d_in[3];
    const float* bias = (const float*)d_in[4];
    float* out = (float*)d_out;
    unsigned short* Wb = (unsigned short*)d_ws;   // 32*768*2 = 48 KB scratch

    prep_w<<<dim3((32*NC + 255)/256), dim3(256), 0, stream>>>(W, Wb);
    tmhs_mfma<<<dim3(NB * NS * 2), dim3(256), 0, stream>>>(p, v, rel, Wb, bias, out);
}